// Round 1
// baseline (517.266 us; speedup 1.0000x reference)
//
#include <hip/hip_runtime.h>
#include <hip/hip_bf16.h>
#include <math.h>

#define B_    32
#define NIN_  2312
#define NHID_ 512
#define NOUT_ 10
#define T_    350
#define KLEN  77      // truncated SRM alpha kernel length (taps 0..76)
#define MAXA  256     // max active inputs per (b,t); Binom(2312,0.03) max ~105

// ---------------- W1 transpose: W1[o][i] -> W1T[i][o] ----------------
__global__ __launch_bounds__(256) void w1t_k(const float* __restrict__ W,
                                             float* __restrict__ WT) {
  __shared__ float tile[32][33];
  int i0 = blockIdx.x * 32, o0 = blockIdx.y * 32;
  int tx = threadIdx.x, tyb = threadIdx.y;
#pragma unroll
  for (int s = 0; s < 4; ++s) {
    int ty = tyb + s * 8;
    int o = o0 + ty, i = i0 + tx;
    if (i < NIN_) tile[ty][tx] = W[(size_t)o * NIN_ + i];
  }
  __syncthreads();
#pragma unroll
  for (int s = 0; s < 4; ++s) {
    int ty = tyb + s * 8;
    int i = i0 + ty, o = o0 + tx;
    if (i < NIN_) WT[(size_t)i * NHID_ + o] = tile[tx][ty];
  }
}

// ------------- compact: per (b,t) list of active input indices -------------
// one wave per (b,i) row; lanes stride over t (coalesced reads of X).
__global__ __launch_bounds__(256) void compact_k(const float* __restrict__ X,
                                                 int* __restrict__ cnt,
                                                 unsigned short* __restrict__ idx) {
  int wave = blockIdx.x * 4 + (threadIdx.x >> 6);
  int lane = threadIdx.x & 63;
  if (wave >= B_ * NIN_) return;
  int b = wave / NIN_, i = wave - b * NIN_;
  const float* row = X + ((size_t)b * NIN_ + i) * T_;
  for (int t = lane; t < T_; t += 64) {
    if (row[t] != 0.0f) {
      int bt = b * T_ + t;
      int pos = atomicAdd(&cnt[bt], 1);
      if (pos < MAXA) idx[(size_t)bt * MAXA + pos] = (unsigned short)i;
    }
  }
}

// ------------- sparse accumulate: Z1[b][t][o] = sum_{active i} W1T[i][o] -------------
// one block per (b,t). Rank-sort the active list (deterministic fp32 sum order).
__global__ __launch_bounds__(256) void accum1_k(const int* __restrict__ cnt,
                                                const unsigned short* __restrict__ idx,
                                                const float* __restrict__ WT,
                                                float* __restrict__ Z1) {
  __shared__ unsigned short raw[MAXA];
  __shared__ unsigned short srt[MAXA];
  int bt = blockIdx.x, tid = threadIdx.x;
  int n = cnt[bt];
  if (n > MAXA) n = MAXA;
  if (tid < n) raw[tid] = idx[(size_t)bt * MAXA + tid];
  __syncthreads();
  if (tid < n) {
    unsigned short v = raw[tid];
    int r = 0;
    for (int j = 0; j < n; ++j) r += (raw[j] < v);
    srt[r] = v;
  }
  __syncthreads();
  float a0 = 0.f, a1 = 0.f;
  for (int j = 0; j < n; ++j) {
    const float* w = WT + (size_t)srt[j] * NHID_;
    a0 += w[tid];
    a1 += w[tid + 256];
  }
  float* zr = Z1 + (size_t)bt * NHID_;
  zr[tid] = a0;
  zr[tid + 256] = a1;
}

// ------------- layer-1 scan: truncated-PSP dual IIR (fp64) + refractory (fp32) -------------
// thread per (b,h). Emits spikes as bits into mask[(b*T+t)*8 + h/64].
__global__ __launch_bounds__(256) void scan1_k(const float* __restrict__ Z1,
                                               unsigned long long* __restrict__ mask) {
  int n = blockIdx.x * 256 + threadIdx.x;   // 0..16383
  int b = n >> 9, h = n & (NHID_ - 1);
  const double dp   = exp(-0.1);            // PSP decay per step
  const double Ap   = exp(1.0) / 10.0;      // kernel scale (e/tau), x Ts=1
  const double D77  = exp(-7.7);            // dp^77
  const float  Dref = (float)exp(-1.0);
  const float  Cref = (float)(-20.0 * exp(1.0));  // -SCALE_REF*THETA*e*Ts/TAU_REF
  double Xc = 0.0, Yc = 0.0, Xd = 0.0, Yd = 0.0;
  float xr = 0.f, yr = 0.f;
  const float* zb = Z1 + (size_t)b * T_ * NHID_ + h;
  unsigned long long* mb = mask + (size_t)b * T_ * 8 + (h >> 6);
  const unsigned long long bit = 1ull << (h & 63);
  float zc = zb[0];
  float zdc = 0.f;
  for (int t = 0; t < T_; ++t) {
    // prefetch next iteration's inputs (hide load latency under compute)
    float zn  = (t + 1 < T_) ? zb[(size_t)(t + 1) * NHID_] : 0.f;
    float zdn = (t + 1 >= KLEN && t + 1 < T_) ? zb[(size_t)(t + 1 - KLEN) * NHID_] : 0.f;
    // current PSP IIR:  Y[t] = d*(Y[t-1]+X[t-1]);  X[t] = d*X[t-1] + z[t]
    Yc = dp * (Yc + Xc); Xc = dp * Xc + (double)zc;
    // delayed-by-K IIR (fed z[t-77]) -> gives X[t-77], Y[t-77]
    Yd = dp * (Yd + Xd); Xd = dp * Xd + (double)zdc;
    // truncated conv:  A*( Y[t] - d^77 * (Y[t-77] + 77*X[t-77]) )
    float p = (float)(Ap * (Yc - D77 * (Yd + 77.0 * Xd)));
    // refractory recurrence, fp32, op-for-op like reference
    yr = Dref * (yr + xr);
    float u = p + Cref * yr;
    float s = (u >= 10.0f) ? 1.0f : 0.0f;
    xr = Dref * xr + s;
    if (s != 0.f) atomicOr(&mb[(size_t)t * 8], bit);
    zc = zn; zdc = zdn;
  }
}

// ------------- layer-2 GEMM via spike bitmask: Z2[b][o][t] = sum_{h set} W2[o][h] -------------
// one wave per (b,t); lanes 0..9 each own one output channel. Bit order => deterministic sum.
__global__ __launch_bounds__(256) void z2_k(const unsigned long long* __restrict__ mask,
                                            const float* __restrict__ W2,
                                            float* __restrict__ Z2) {
  int wave = blockIdx.x * 4 + (threadIdx.x >> 6);
  int lane = threadIdx.x & 63;
  if (wave >= B_ * T_) return;
  int b = wave / T_, t = wave - b * T_;
  const unsigned long long* m = mask + (size_t)wave * 8;
  if (lane < NOUT_) {
    const float* wr = W2 + (size_t)lane * NHID_;
    float acc = 0.f;
#pragma unroll
    for (int w = 0; w < 8; ++w) {
      unsigned long long mm = m[w];
      while (mm) {
        int j = __builtin_ctzll(mm);
        mm &= mm - 1;
        acc += wr[w * 64 + j];
      }
    }
    Z2[((size_t)b * NOUT_ + lane) * T_ + t] = acc;
  }
}

// ------------- layer-2 scan -> output spikes -------------
__global__ __launch_bounds__(64) void scan2_k(const float* __restrict__ Z2,
                                              float* __restrict__ out) {
  int n = blockIdx.x * 64 + threadIdx.x;    // n = b*NOUT + o
  if (n >= B_ * NOUT_) return;
  const double dp   = exp(-0.1);
  const double Ap   = exp(1.0) / 10.0;
  const double D77  = exp(-7.7);
  const float  Dref = (float)exp(-1.0);
  const float  Cref = (float)(-20.0 * exp(1.0));
  double Xc = 0.0, Yc = 0.0, Xd = 0.0, Yd = 0.0;
  float xr = 0.f, yr = 0.f;
  const float* row = Z2 + (size_t)n * T_;
  float* orow = out + (size_t)n * T_;
  float zc = row[0];
  float zdc = 0.f;
  for (int t = 0; t < T_; ++t) {
    float zn  = (t + 1 < T_) ? row[t + 1] : 0.f;
    float zdn = (t + 1 >= KLEN && t + 1 < T_) ? row[t + 1 - KLEN] : 0.f;
    Yc = dp * (Yc + Xc); Xc = dp * Xc + (double)zc;
    Yd = dp * (Yd + Xd); Xd = dp * Xd + (double)zdc;
    float p = (float)(Ap * (Yc - D77 * (Yd + 77.0 * Xd)));
    yr = Dref * (yr + xr);
    float u = p + Cref * yr;
    float s = (u >= 10.0f) ? 1.0f : 0.0f;
    xr = Dref * xr + s;
    orow[t] = s;   // spk / Ts, Ts = 1
    zc = zn; zdc = zdn;
  }
}

extern "C" void kernel_launch(void* const* d_in, const int* in_sizes, int n_in,
                              void* d_out, int out_size, void* d_ws, size_t ws_size,
                              hipStream_t stream) {
  const float* X  = (const float*)d_in[0];  // (32, 2312, 350)
  const float* W1 = (const float*)d_in[1];  // (512, 2312)
  const float* W2 = (const float*)d_in[2];  // (10, 512)
  float* out = (float*)d_out;               // (32, 10, 350)

  char* ws = (char*)d_ws;
  size_t off = 0;
  float* W1T = (float*)(ws + off);                 off += (size_t)NIN_ * NHID_ * 4;       // 4.73 MB
  int* cnt = (int*)(ws + off);                     off += (size_t)B_ * T_ * 4;            // 44.8 KB
  unsigned short* idx = (unsigned short*)(ws + off); off += (size_t)B_ * T_ * MAXA * 2;   // 5.73 MB
  float* Z1 = (float*)(ws + off);                  off += (size_t)B_ * T_ * NHID_ * 4;    // 22.9 MB
  unsigned long long* mask = (unsigned long long*)(ws + off); off += (size_t)B_ * T_ * 8 * 8; // 0.72 MB
  float* Z2 = (float*)(ws + off);                  off += (size_t)B_ * NOUT_ * T_ * 4;    // 0.45 MB
  if (off > ws_size) return;  // workspace too small -> fail loudly (no launches)

  hipMemsetAsync(cnt, 0, (size_t)B_ * T_ * 4, stream);
  hipMemsetAsync(mask, 0, (size_t)B_ * T_ * 8 * 8, stream);

  w1t_k<<<dim3((NIN_ + 31) / 32, NHID_ / 32), dim3(32, 8), 0, stream>>>(W1, W1T);
  compact_k<<<(B_ * NIN_ + 3) / 4, 256, 0, stream>>>(X, cnt, idx);
  accum1_k<<<B_ * T_, 256, 0, stream>>>(cnt, idx, W1T, Z1);
  scan1_k<<<(B_ * NHID_) / 256, 256, 0, stream>>>(Z1, mask);
  z2_k<<<(B_ * T_ + 3) / 4, 256, 0, stream>>>(mask, W2, Z2);
  scan2_k<<<(B_ * NOUT_ + 63) / 64, 64, 0, stream>>>(Z2, out);
}

// Round 3
// 416.863 us; speedup vs baseline: 1.2409x; 1.2409x over previous
//
#include <hip/hip_runtime.h>
#include <hip/hip_bf16.h>
#include <math.h>

#define B_    32
#define NIN_  2312
#define NHID_ 512
#define NOUT_ 10
#define T_    350
#define KLEN  77      // truncated SRM alpha kernel length (taps 0..76)
#define MW    40      // u64 words per (b,t) input mask row (37 used, padded)
#define MAXA2 320     // max active inputs per (b,t); Binom(2312,0.03) max ~110

// ---------------- W1 transpose: W1[o][i] -> W1T[i][o] ----------------
__global__ __launch_bounds__(256) void w1t_k(const float* __restrict__ W,
                                             float* __restrict__ WT) {
  __shared__ float tile[32][33];
  int i0 = blockIdx.x * 32, o0 = blockIdx.y * 32;
  int tx = threadIdx.x, tyb = threadIdx.y;
#pragma unroll
  for (int s = 0; s < 4; ++s) {
    int ty = tyb + s * 8;
    int o = o0 + ty, i = i0 + tx;
    if (i < NIN_) tile[ty][tx] = W[(size_t)o * NIN_ + i];
  }
  __syncthreads();
#pragma unroll
  for (int s = 0; s < 4; ++s) {
    int ty = tyb + s * 8;
    int i = i0 + ty, o = o0 + tx;
    if (i < NIN_) WT[(size_t)i * NHID_ + o] = tile[tx][ty];
  }
}

// ------------- input bitmask: bit i of msk[b][t][i/64] = (X[b][i][t] != 0) -------------
// one wave per (b,i) row; lanes stride over t as float2 (coalesced). OR is
// commutative -> deterministic result regardless of atomic order.
__global__ __launch_bounds__(256) void inmask_k(const float* __restrict__ X,
                                                unsigned long long* __restrict__ msk) {
  int wave = blockIdx.x * 4 + (threadIdx.x >> 6);
  int lane = threadIdx.x & 63;
  if (wave >= B_ * NIN_) return;
  int b = wave / NIN_, i = wave - b * NIN_;
  const float2* row = (const float2*)(X + (size_t)wave * T_);   // row offset even -> 8B aligned
  const unsigned long long bit = 1ull << (i & 63);
  unsigned long long* mb = msk + (size_t)b * T_ * MW + (i >> 6);
  for (int p = lane; p < T_ / 2; p += 64) {
    float2 v = row[p];
    if (v.x != 0.f) atomicOr(&mb[(size_t)(2 * p) * MW], bit);
    if (v.y != 0.f) atomicOr(&mb[(size_t)(2 * p + 1) * MW], bit);
  }
}

// ------------- sparse accumulate: Z1[b][t][o] = sum_{active i, ascending} W1T[i][o] -------------
// one block per (b,t). Expand bitmask -> ascending index list (deterministic order,
// identical to the round-1 rank-sorted order), then gather rows as float2.
__global__ __launch_bounds__(256) void accum1_k(const unsigned long long* __restrict__ msk,
                                                const float* __restrict__ WT,
                                                float* __restrict__ Z1) {
  __shared__ unsigned short list[MAXA2];
  __shared__ int ntot;
  int bt = blockIdx.x, tid = threadIdx.x;
  if (tid < 64) {
    unsigned long long w = (tid < 37) ? msk[(size_t)bt * MW + tid] : 0ull;
    int pc = __popcll(w);
    int pre = pc;
#pragma unroll
    for (int d = 1; d < 64; d <<= 1) {
      int o = __shfl_up(pre, d);
      if (tid >= d) pre += o;
    }
    int base = pre - pc;                  // exclusive prefix
    if (tid == 63) ntot = pre;            // inclusive at last lane = total
    while (w) {
      int j = __builtin_ctzll(w);
      if (base < MAXA2) list[base] = (unsigned short)(tid * 64 + j);
      ++base;
      w &= w - 1;
    }
  }
  __syncthreads();
  int n = ntot;
  if (n > MAXA2) n = MAXA2;
  float a0 = 0.f, a1 = 0.f;
#pragma unroll 4
  for (int j = 0; j < n; ++j) {
    const float2* w2 = (const float2*)(WT + (size_t)list[j] * NHID_);
    float2 v = w2[tid];
    a0 += v.x;                            // strict ascending-i order per output element
    a1 += v.y;
  }
  float2* zr = (float2*)(Z1 + (size_t)bt * NHID_);
  zr[tid] = make_float2(a0, a1);
}

// ------------- layer-1 scan: truncated-PSP dual IIR (fp64) + refractory (fp32) -------------
// 64-thread blocks, one wave per (b, h-group-of-64). 16-deep register prefetch;
// spikes recorded via per-wave ballot (wave exclusively owns its mask word -> plain store).
__global__ __launch_bounds__(64) void scan1_k(const float* __restrict__ Z1,
                                              unsigned long long* __restrict__ mask) {
  int lane = threadIdx.x;
  int b = blockIdx.x >> 3, g = blockIdx.x & 7;
  int h = g * 64 + lane;
  const double dp   = exp(-0.1);            // PSP decay per step
  const double Ap   = exp(1.0) / 10.0;      // kernel scale (e/tau) x Ts
  const double D77  = exp(-7.7);            // dp^77
  const float  Dref = (float)exp(-1.0);
  const float  Cref = (float)(-20.0 * exp(1.0));  // -SCALE_REF*THETA*e*Ts/TAU_REF
  double Xc = 0.0, Yc = 0.0, Xd = 0.0, Yd = 0.0;
  float xr = 0.f, yr = 0.f;
  const float* zb = Z1 + (size_t)b * T_ * NHID_ + h;
  unsigned long long* mb = mask + (size_t)b * T_ * 8 + g;
  for (int t0 = 0; t0 < T_; t0 += 16) {
    float z[16], zd[16];
#pragma unroll
    for (int k = 0; k < 16; ++k) {
      int t = t0 + k;
      z[k]  = (t < T_) ? zb[(size_t)t * NHID_] : 0.f;
      zd[k] = (t >= KLEN && t < T_) ? zb[(size_t)(t - KLEN) * NHID_] : 0.f;
    }
#pragma unroll
    for (int k = 0; k < 16; ++k) {
      int t = t0 + k;
      if (t >= T_) break;                 // uniform
      Yc = dp * (Yc + Xc); Xc = dp * Xc + (double)z[k];
      Yd = dp * (Yd + Xd); Xd = dp * Xd + (double)zd[k];
      float p = (float)(Ap * (Yc - D77 * (Yd + 77.0 * Xd)));
      yr = Dref * (yr + xr);
      float u = p + Cref * yr;
      float s = (u >= 10.0f) ? 1.0f : 0.0f;
      xr = Dref * xr + s;
      unsigned long long bw = __ballot(u >= 10.0f);
      if (lane == 0) mb[(size_t)t * 8] = bw;
    }
  }
}

// ------------- layer-2 GEMM via spike bitmask: Z2[b][o][t] = sum_{h set, ascending} W2[o][h] -------------
__global__ __launch_bounds__(256) void z2_k(const unsigned long long* __restrict__ mask,
                                            const float* __restrict__ W2,
                                            float* __restrict__ Z2) {
  int wave = blockIdx.x * 4 + (threadIdx.x >> 6);
  int lane = threadIdx.x & 63;
  if (wave >= B_ * T_) return;
  int b = wave / T_, t = wave - b * T_;
  const unsigned long long* m = mask + (size_t)wave * 8;
  if (lane < NOUT_) {
    const float* wr = W2 + (size_t)lane * NHID_;
    float acc = 0.f;
#pragma unroll
    for (int w = 0; w < 8; ++w) {
      unsigned long long mm = m[w];
      while (mm) {
        int j = __builtin_ctzll(mm);
        mm &= mm - 1;
        acc += wr[w * 64 + j];
      }
    }
    Z2[((size_t)b * NOUT_ + lane) * T_ + t] = acc;
  }
}

// ------------- layer-2 scan -> output spikes -------------
__global__ __launch_bounds__(64) void scan2_k(const float* __restrict__ Z2,
                                              float* __restrict__ out) {
  int n = blockIdx.x * 64 + threadIdx.x;    // n = b*NOUT + o
  if (n >= B_ * NOUT_) return;
  const double dp   = exp(-0.1);
  const double Ap   = exp(1.0) / 10.0;
  const double D77  = exp(-7.7);
  const float  Dref = (float)exp(-1.0);
  const float  Cref = (float)(-20.0 * exp(1.0));
  double Xc = 0.0, Yc = 0.0, Xd = 0.0, Yd = 0.0;
  float xr = 0.f, yr = 0.f;
  const float* row = Z2 + (size_t)n * T_;
  float* orow = out + (size_t)n * T_;
  float zc = row[0];
  float zdc = 0.f;
  for (int t = 0; t < T_; ++t) {
    float zn  = (t + 1 < T_) ? row[t + 1] : 0.f;
    float zdn = (t + 1 >= KLEN && t + 1 < T_) ? row[t + 1 - KLEN] : 0.f;
    Yc = dp * (Yc + Xc); Xc = dp * Xc + (double)zc;
    Yd = dp * (Yd + Xd); Xd = dp * Xd + (double)zdc;
    float p = (float)(Ap * (Yc - D77 * (Yd + 77.0 * Xd)));
    yr = Dref * (yr + xr);
    float u = p + Cref * yr;
    float s = (u >= 10.0f) ? 1.0f : 0.0f;
    xr = Dref * xr + s;
    orow[t] = s;   // spk / Ts, Ts = 1
    zc = zn; zdc = zdn;
  }
}

extern "C" void kernel_launch(void* const* d_in, const int* in_sizes, int n_in,
                              void* d_out, int out_size, void* d_ws, size_t ws_size,
                              hipStream_t stream) {
  const float* X  = (const float*)d_in[0];  // (32, 2312, 350)
  const float* W1 = (const float*)d_in[1];  // (512, 2312)
  const float* W2 = (const float*)d_in[2];  // (10, 512)
  float* out = (float*)d_out;               // (32, 10, 350)

  char* ws = (char*)d_ws;
  size_t off = 0;
  float* W1T = (float*)(ws + off);                 off += (size_t)NIN_ * NHID_ * 4;         // 4.73 MB
  unsigned long long* msk = (unsigned long long*)(ws + off); off += (size_t)B_ * T_ * MW * 8; // 3.58 MB
  float* Z1 = (float*)(ws + off);                  off += (size_t)B_ * T_ * NHID_ * 4;      // 22.9 MB
  unsigned long long* mask = (unsigned long long*)(ws + off); off += (size_t)B_ * T_ * 8 * 8; // 0.72 MB
  float* Z2 = (float*)(ws + off);                  off += (size_t)B_ * NOUT_ * T_ * 4;      // 0.45 MB
  if (off > ws_size) return;  // workspace too small -> fail loudly (no launches)

  hipMemsetAsync(msk, 0, (size_t)B_ * T_ * MW * 8, stream);

  w1t_k<<<dim3((NIN_ + 31) / 32, NHID_ / 32), dim3(32, 8), 0, stream>>>(W1, W1T);
  inmask_k<<<(B_ * NIN_ + 3) / 4, 256, 0, stream>>>(X, msk);
  accum1_k<<<B_ * T_, 256, 0, stream>>>(msk, W1T, Z1);
  scan1_k<<<B_ * 8, 64, 0, stream>>>(Z1, mask);
  z2_k<<<(B_ * T_ + 3) / 4, 256, 0, stream>>>(mask, W2, Z2);
  scan2_k<<<(B_ * NOUT_ + 63) / 64, 64, 0, stream>>>(Z2, out);
}